// Round 5
// baseline (248.634 us; speedup 1.0000x reference)
//
#include <hip/hip_runtime.h>
#include <stdint.h>

// Problem constants (reference: N=500000, F_IN=10, HID=32, OUT=2, d_in=42)
// Settled world model: all tensors f32 on device; harness threshold 0.088
// (bf16 floor). Outputs flat f32: out [N,2] at [0,1e6), h_new [N,32] after.
//
// R8 (MFMA rewrite): 126.6 -> 54.0 us. R9 (this): attack the measured
// 3.6M LDS bank-conflict cycles + scalar-LDS head matvec + redundant
// per-mt weight fragment re-reads.
//   * LDS row stride 96B -> 112B (56 u16). 112=16*7: rows stay 16B-aligned
//     and fragment reads (lo16*28+g*4)%32 spread uniformly over all bank
//     groups -> conflict-free (old stride-24-dword pattern was 4-way on
//     fragments, 16-way on the head's scalar column walk).
//   * Head = 1 extra MFMA per mt: relu(h_new) bf16 stashed into dead cols
//     0-31 (x consumed after GEMM2), A-frag read K=32 exact, B = Wl bf16
//     (cols 2-15 zero). Removes 32 conflicted scalar LDS reads + ~100 VALU
//     per thread.
//   * All weight B-fragments hoisted out of the mt loop into regs (13
//     short8 = 52 VGPR). LDS caps occupancy at 4 blocks/CU = 4 waves/SIMD,
//     which tolerates <=128 VGPR -> redundant LDS B-reads were pure waste.
// Fragment layouts (gfx950 16x16x32 bf16): A row=l&15, k=(l>>4)*8+i;
// B col=l&15, k=(l>>4)*8+i; C/D col=l&15, row=(l>>4)*4+q (HW-verified map).
static constexpr int N_NODES = 500000;
static constexpr int STR     = 56;     // LDS row stride in u16 (112 B)

typedef __attribute__((ext_vector_type(8))) short short8;   // 8 bf16, 4 VGPRs
typedef __attribute__((ext_vector_type(4))) float f32x4;

// d_ws layout:
//   u16 [0, 3584):    wzr bf16 [64 cols][56 k]  (z cols 0-31, r cols 32-63)
//   u16 [3584, 5376): wh  bf16 [32 cols][56 k]  (k 42-55 zeroed)
//   u16 [5376, 5440): Wl  bf16 [2][32]
//   f32 [2720): bz[32]  [2752): br[32]  [2784): bh[32]
//   f32 [2816): bl[2]   [2818): x_f32 flag  [2819): h_f32 flag

__device__ __forceinline__ float bfdec(uint32_t b){
  union{uint32_t u; float f;} c; c.u = b << 16; return c.f;
}
__device__ __forceinline__ uint32_t bfrne(float f){   // f32 -> bf16 (RNE)
  union{float f; uint32_t u;} c; c.f = f;
  return (c.u + 0x7fffu + ((c.u >> 16) & 1u)) >> 16;
}
__device__ __forceinline__ uint32_t pack2(float a, float b){
  return bfrne(a) | (bfrne(b) << 16);
}
__device__ __forceinline__ float sigmoid_fast(float x){
  float e = __expf(-x);
  return __builtin_amdgcn_rcpf(1.0f + e);
}
__device__ __forceinline__ float tanh_fast(float x){
  float e = __expf(2.0f * x);
  return 1.0f - 2.0f * __builtin_amdgcn_rcpf(e + 1.0f);
}

// bf16-packed data: lo u16 decodes to |v| <~ 6; f32 data: lo u16 is random
// mantissa bits -> decoded exponent uniform -> max explodes past 1e6 w.p.~1.
__device__ bool detect_f32_words(const uint32_t* w, int K){
  float m = 0.0f;
  for (int i = 0; i < K; i++) m = fmaxf(m, fabsf(bfdec(w[i] & 0xffffu)));
  return !(m < 1e6f);   // NaN-safe: NaN => f32
}
__device__ __forceinline__ float wload(const void* p, int idx, bool f32w){
  if (f32w) return ((const float*)p)[idx];
  return bfdec(((const uint16_t*)p)[idx]);
}

__global__ void prep_kernel(const void* __restrict__ Wz,
                            const void* __restrict__ bz,
                            const void* __restrict__ Wr,
                            const void* __restrict__ br,
                            const void* __restrict__ Wh,
                            const void* __restrict__ bh,
                            const void* __restrict__ Wl,
                            const void* __restrict__ bl,
                            const uint32_t* __restrict__ xg,
                            const uint32_t* __restrict__ hg,
                            float* __restrict__ ws)
{
  const bool f32w = detect_f32_words((const uint32_t*)Wz, 64);
  uint16_t* wsh = (uint16_t*)ws;
  float*    wsf = ws;
  int i = blockIdx.x * 256 + threadIdx.x;
  if (i < 5376) {
    // bf16 weight tables, transposed+combined: Wt[col][k] = W[0][k][col]+W[1][k][col]
    float v = 0.0f;
    if (i < 3584) {                 // wzr: col 0-31 = z, 32-63 = r
      int col = i / STR, k = i - col * STR;
      if (k < 42) {
        const void* Wp = (col < 32) ? Wz : Wr;
        int j = (col < 32) ? col : col - 32;
        int src = k * 32 + j;
        v = wload(Wp, src, f32w) + wload(Wp, 1344 + src, f32w);
      }
    } else {                        // wh
      int t2 = i - 3584;
      int col = t2 / STR, k = t2 - col * STR;
      if (k < 42) {
        int src = k * 32 + col;
        v = wload(Wh, src, f32w) + wload(Wh, 1344 + src, f32w);
      }
    }
    wsh[i] = (uint16_t)bfrne(v);
  } else if (i < 5440) {
    int r = i - 5376;               // r = c*32 + k, matches Wl [2][32] row-major
    wsh[i] = (uint16_t)bfrne(wload(Wl, r, f32w));
  } else if (i < 5538) {
    int r = i - 5440;
    if      (r < 32) wsf[2720 + r]      = wload(bz, r,     f32w);
    else if (r < 64) wsf[2752 + (r-32)] = wload(br, r-32,  f32w);
    else if (r < 96) wsf[2784 + (r-64)] = wload(bh, r-64,  f32w);
    else             wsf[2816 + (r-96)] = wload(bl, r-96,  f32w);
  } else if (i == 5568) {
    wsf[2818] = detect_f32_words(xg, 256) ? 1.0f : 0.0f;
  } else if (i == 5569) {
    wsf[2819] = detect_f32_words(hg, 256) ? 1.0f : 0.0f;
  }
}

__global__ __launch_bounds__(256, 4) void dcrnn_kernel(
    const uint32_t* __restrict__ xg,    // x [N,10]: f32 or bf16-packed
    const uint32_t* __restrict__ hg,    // h [N,32]: f32 or bf16-packed
    const float*    __restrict__ ws,
    float* __restrict__ out0,           // f32 [N,2]
    float* __restrict__ outh)           // f32 [N,32]
{
  __shared__ __align__(16) uint16_t w_u16[96 * STR];    // 10752 B weights
  __shared__ __align__(16) uint16_t xh_u16[256 * STR];  // 28672 B A-tile

  const int t  = threadIdx.x;
  const int nd = blockIdx.x * 256 + t;
  const bool valid = nd < N_NODES;
  const float* wsf = ws;
  const bool x_f32 = wsf[2818] != 0.0f;
  const bool h_f32 = wsf[2819] != 0.0f;

  // ---- stage weights (block-cooperative): 10752 B = 672 uint4 ----
  const uint4* wsq = (const uint4*)ws;
  for (int i = t; i < 672; i += 256) ((uint4*)w_u16)[i] = wsq[i];

  // ---- stage this thread's node row: bf16 cols 0-9 x, 10-41 h, 42-47 pad ----
  uint32_t rw[24];
  #pragma unroll
  for (int i = 0; i < 24; i++) rw[i] = 0u;
  if (valid) {
    if (x_f32) {
      const float2* xr = (const float2*)((const float*)xg + (size_t)nd * 10);
      #pragma unroll
      for (int i = 0; i < 5; i++){ float2 v = xr[i]; rw[i] = pack2(v.x, v.y); }
    } else {
      const uint32_t* xr = xg + (size_t)nd * 5;
      #pragma unroll
      for (int i = 0; i < 5; i++) rw[i] = xr[i];     // already 2×bf16 per u32
    }
    if (h_f32) {
      const float4* hr = (const float4*)((const float*)hg + (size_t)nd * 32);
      #pragma unroll
      for (int i = 0; i < 8; i++){
        float4 v = hr[i];
        rw[5 + 2*i]     = pack2(v.x, v.y);
        rw[5 + 2*i + 1] = pack2(v.z, v.w);
      }
    } else {
      const uint4* hr = (const uint4*)(hg + (size_t)nd * 16);
      #pragma unroll
      for (int i = 0; i < 4; i++){
        uint4 v = hr[i];
        rw[5 + 4*i]     = v.x; rw[5 + 4*i + 1] = v.y;
        rw[5 + 4*i + 2] = v.z; rw[5 + 4*i + 3] = v.w;
      }
    }
  }
  {
    uint4* dst = (uint4*)(xh_u16 + t * STR);   // t*112 B, 16B-aligned
    #pragma unroll
    for (int c = 0; c < 6; c++)
      dst[c] = make_uint4(rw[4*c], rw[4*c+1], rw[4*c+2], rw[4*c+3]);
  }
  __syncthreads();

  // ---- per-wave MFMA pipeline: wave w owns rows [64w, 64w+64) ----
  const int l = t & 63, w = t >> 6;
  const int lo16 = l & 15, g = l >> 4;
  uint16_t* xwm = xh_u16 + (w * 64) * STR;

  const float bzc0 = wsf[2720 + lo16], bzc1 = wsf[2736 + lo16];
  const float brc0 = wsf[2752 + lo16], brc1 = wsf[2768 + lo16];
  const float bhc0 = wsf[2784 + lo16], bhc1 = wsf[2800 + lo16];
  const float blc  = (lo16 < 2) ? wsf[2816 + lo16] : 0.0f;

  const short8 zero8 = {0,0,0,0,0,0,0,0};

  // ---- hoist ALL weight B-fragments into registers (loop-invariant) ----
  short8 bzr_lo[4], bzr_hi[4];          // GEMM1: nt=0,1 -> z; nt=2,3 -> r
  #pragma unroll
  for (int nt = 0; nt < 4; nt++){
    const uint16_t* brow = w_u16 + (nt*16 + lo16) * STR;
    bzr_lo[nt] = *(const short8*)(brow + g*8);
    bzr_hi[nt] = zero8;
    if (g < 2) bzr_hi[nt] = *(const short8*)(brow + 32 + g*8);
  }
  short8 bh_lo[2], bh_hi[2];            // GEMM2
  #pragma unroll
  for (int nt = 0; nt < 2; nt++){
    const uint16_t* brow = w_u16 + 3584 + (nt*16 + lo16) * STR;
    bh_lo[nt] = *(const short8*)(brow + g*8);
    bh_hi[nt] = zero8;
    if (g < 2) bh_hi[nt] = *(const short8*)(brow + 32 + g*8);
  }
  short8 bO = zero8;                    // head: Wl bf16, cols 2-15 zero
  if (lo16 < 2) bO = *(const short8*)((const uint16_t*)ws + 5376 + lo16*32 + g*8);

  #pragma unroll
  for (int mt = 0; mt < 4; mt++){
    const uint16_t* arow = xwm + (mt*16 + lo16) * STR;
    short8 a0 = *(const short8*)(arow + g*8);
    short8 a1 = zero8;
    if (g < 2) a1 = *(const short8*)(arow + 32 + g*8);

    // GEMM1: z (cols 0-31) and r (cols 32-63) preacts, bias in acc init
    f32x4 accZ0 = {bzc0,bzc0,bzc0,bzc0};
    f32x4 accZ1 = {bzc1,bzc1,bzc1,bzc1};
    f32x4 accR0 = {brc0,brc0,brc0,brc0};
    f32x4 accR1 = {brc1,brc1,brc1,brc1};
    accZ0 = __builtin_amdgcn_mfma_f32_16x16x32_bf16(a0, bzr_lo[0], accZ0, 0,0,0);
    accZ0 = __builtin_amdgcn_mfma_f32_16x16x32_bf16(a1, bzr_hi[0], accZ0, 0,0,0);
    accZ1 = __builtin_amdgcn_mfma_f32_16x16x32_bf16(a0, bzr_lo[1], accZ1, 0,0,0);
    accZ1 = __builtin_amdgcn_mfma_f32_16x16x32_bf16(a1, bzr_hi[1], accZ1, 0,0,0);
    accR0 = __builtin_amdgcn_mfma_f32_16x16x32_bf16(a0, bzr_lo[2], accR0, 0,0,0);
    accR0 = __builtin_amdgcn_mfma_f32_16x16x32_bf16(a1, bzr_hi[2], accR0, 0,0,0);
    accR1 = __builtin_amdgcn_mfma_f32_16x16x32_bf16(a0, bzr_lo[3], accR1, 0,0,0);
    accR1 = __builtin_amdgcn_mfma_f32_16x16x32_bf16(a1, bzr_hi[3], accR1, 0,0,0);

    // rh pass: save h (f32 from bf16), overwrite LDS cols 10-41 with r*h
    f32x4 hs0, hs1;
    #pragma unroll
    for (int q = 0; q < 4; q++){
      int row = mt*16 + g*4 + q;
      uint16_t* p0 = xwm + row*STR + 10 + lo16;
      uint16_t* p1 = xwm + row*STR + 26 + lo16;
      float h0 = bfdec(*p0), h1 = bfdec(*p1);
      float r0 = sigmoid_fast(accR0[q]);
      float r1 = sigmoid_fast(accR1[q]);
      *p0 = (uint16_t)bfrne(r0 * h0);
      *p1 = (uint16_t)bfrne(r1 * h1);
      hs0[q] = h0; hs1[q] = h1;
    }
    asm volatile("s_waitcnt lgkmcnt(0)" ::: "memory");  // cross-lane LDS RAW

    // GEMM2: h_tilde preacts from [x | r*h]
    f32x4 accH0 = {bhc0,bhc0,bhc0,bhc0};
    f32x4 accH1 = {bhc1,bhc1,bhc1,bhc1};
    short8 c0 = *(const short8*)(arow + g*8);
    short8 c1 = zero8;
    if (g < 2) c1 = *(const short8*)(arow + 32 + g*8);
    accH0 = __builtin_amdgcn_mfma_f32_16x16x32_bf16(c0, bh_lo[0], accH0, 0,0,0);
    accH0 = __builtin_amdgcn_mfma_f32_16x16x32_bf16(c1, bh_hi[0], accH0, 0,0,0);
    accH1 = __builtin_amdgcn_mfma_f32_16x16x32_bf16(c0, bh_lo[1], accH1, 0,0,0);
    accH1 = __builtin_amdgcn_mfma_f32_16x16x32_bf16(c1, bh_hi[1], accH1, 0,0,0);

    // blend + store h_new (f32); stash relu(h_new) bf16 into dead cols 0-31
    #pragma unroll
    for (int q = 0; q < 4; q++){
      int row  = mt*16 + g*4 + q;
      int node = blockIdx.x*256 + w*64 + row;
      float z0 = sigmoid_fast(accZ0[q]);
      float z1 = sigmoid_fast(accZ1[q]);
      float t0 = tanh_fast(accH0[q]);
      float t1 = tanh_fast(accH1[q]);
      float hn0 = fmaf(z0, hs0[q] - t0, t0);
      float hn1 = fmaf(z1, hs1[q] - t1, t1);
      if (node < N_NODES){
        outh[(size_t)node*32 + lo16]      = hn0;
        outh[(size_t)node*32 + 16 + lo16] = hn1;
      }
      *(xwm + row*STR + lo16)      = (uint16_t)bfrne(fmaxf(hn0, 0.0f));
      *(xwm + row*STR + 16 + lo16) = (uint16_t)bfrne(fmaxf(hn1, 0.0f));
    }
    asm volatile("s_waitcnt lgkmcnt(0)" ::: "memory");  // stash visible in-wave

    // head: one MFMA — relu(h_new)[16x32] @ Wl^T[32x2] (cols 2-15 waste)
    short8 aO = *(const short8*)(arow + g*8);           // cols g*8..g*8+7
    f32x4 accO = {blc, blc, blc, blc};
    accO = __builtin_amdgcn_mfma_f32_16x16x32_bf16(aO, bO, accO, 0,0,0);
    #pragma unroll
    for (int q = 0; q < 4; q++){
      int node = blockIdx.x*256 + w*64 + mt*16 + g*4 + q;
      if (lo16 < 2 && node < N_NODES)
        out0[(size_t)node*2 + lo16] = accO[q];
    }
  }
}

extern "C" void kernel_launch(void* const* d_in, const int* in_sizes, int n_in,
                              void* d_out, int out_size, void* d_ws, size_t ws_size,
                              hipStream_t stream) {
  // setup_inputs order:
  // 0:x 1:edge_index(unused) 2:edge_weight(unused) 3:h
  // 4:W_z 5:b_z 6:W_r 7:b_r 8:W_h 9:b_h 10:W_lin 11:b_lin
  const uint32_t* x = (const uint32_t*)d_in[0];
  const uint32_t* h = (const uint32_t*)d_in[3];

  float* ws = (float*)d_ws;   // ~11.3 KB used

  prep_kernel<<<22, 256, 0, stream>>>(d_in[4], d_in[5], d_in[6], d_in[7],
                                      d_in[8], d_in[9], d_in[10], d_in[11],
                                      x, h, ws);

  float* outf = (float*)d_out;
  float* out0 = outf;                              // out   [N,2]  f32
  float* outh = outf + (size_t)2 * N_NODES;        // h_new [N,32] f32
  dcrnn_kernel<<<(N_NODES + 255) / 256, 256, 0, stream>>>(
      x, h, ws, out0, outh);
}

// Round 6
// 243.487 us; speedup vs baseline: 1.0211x; 1.0211x over previous
//
#include <hip/hip_runtime.h>
#include <stdint.h>

// Problem constants (reference: N=500000, F_IN=10, HID=32, OUT=2, d_in=42)
// Settled world model: all tensors f32 on device; harness threshold 0.088
// (bf16 floor). Outputs flat f32: out [N,2] at [0,1e6), h_new [N,32] after.
//
// Ladder: R8 MFMA rewrite 126.6 -> 54.0 us. R9 (stride fix + head MFMA)
// REGRESSED to 61.5: conflicts 3.6M -> 0.78M but the head MFMA's scattered
// out0 stores (8 lanes x 4B, 32B apart) caused partial-sector RMW:
// WRITE 66->82MB, FETCH 41->49MB. R10: occupancy attack.
//   Evidence: all pipes <33% busy (Mfma 4%, VALU 28%, HBM 27%) ->
//   latency-bound; LDS 39.4KB capped residency at 4 blocks/CU (Occ 32%).
//   * weights NOT staged in LDS: B-fragments read once per wave straight
//     from the 10.75KB ws table (L2-resident, shared across blocks).
//   * 128-thread blocks: A-tile 128x112B = 14.3KB LDS -> 11 blocks/CU
//     = 22 waves/CU (~69% occ ceiling), 2.2x current residency.
//   * head back to per-thread + coalesced float2 out0 (R8 style), but
//     relu(h_new) stashed bf16 into cols 0..31 so the head reads its OWN
//     row via 4x aligned ds_read_b128 (no 16-way column walk).
// Fragment layouts (gfx950 16x16x32 bf16): A row=l&15, k=(l>>4)*8+i;
// B col=l&15, k=(l>>4)*8+i; C/D col=l&15, row=(l>>4)*4+q (HW-verified map).
static constexpr int N_NODES = 500000;
static constexpr int STR     = 56;     // LDS/ws row stride in u16 (112 B)

typedef __attribute__((ext_vector_type(8))) short short8;   // 8 bf16, 4 VGPRs
typedef __attribute__((ext_vector_type(4))) float f32x4;

// d_ws layout:
//   u16 [0, 3584):    wzr bf16 [64 cols][56 k]  (z cols 0-31, r cols 32-63)
//   u16 [3584, 5376): wh  bf16 [32 cols][56 k]  (k 42-55 zeroed)
//   f32 [2688): bz[32]  [2720): br[32]  [2752): bh[32]
//   f32 [2784): Wl[64]  [2848): bl[2]  [2850): x_f32 flag  [2851): h_f32 flag

__device__ __forceinline__ float bfdec(uint32_t b){
  union{uint32_t u; float f;} c; c.u = b << 16; return c.f;
}
__device__ __forceinline__ float bf_lo(uint32_t u){ union{uint32_t u; float f;} c; c.u = u << 16; return c.f; }
__device__ __forceinline__ float bf_hi(uint32_t u){ union{uint32_t u; float f;} c; c.u = u & 0xffff0000u; return c.f; }
__device__ __forceinline__ uint32_t bfrne(float f){   // f32 -> bf16 (RNE)
  union{float f; uint32_t u;} c; c.f = f;
  return (c.u + 0x7fffu + ((c.u >> 16) & 1u)) >> 16;
}
__device__ __forceinline__ uint32_t pack2(float a, float b){
  return bfrne(a) | (bfrne(b) << 16);
}
__device__ __forceinline__ float sigmoid_fast(float x){
  float e = __expf(-x);
  return __builtin_amdgcn_rcpf(1.0f + e);
}
__device__ __forceinline__ float tanh_fast(float x){
  float e = __expf(2.0f * x);
  return 1.0f - 2.0f * __builtin_amdgcn_rcpf(e + 1.0f);
}

// bf16-packed data: lo u16 decodes to |v| <~ 6; f32 data: lo u16 is random
// mantissa bits -> decoded exponent uniform -> max explodes past 1e6 w.p.~1.
__device__ bool detect_f32_words(const uint32_t* w, int K){
  float m = 0.0f;
  for (int i = 0; i < K; i++) m = fmaxf(m, fabsf(bfdec(w[i] & 0xffffu)));
  return !(m < 1e6f);   // NaN-safe: NaN => f32
}
__device__ __forceinline__ float wload(const void* p, int idx, bool f32w){
  if (f32w) return ((const float*)p)[idx];
  return bfdec(((const uint16_t*)p)[idx]);
}

__global__ void prep_kernel(const void* __restrict__ Wz,
                            const void* __restrict__ bz,
                            const void* __restrict__ Wr,
                            const void* __restrict__ br,
                            const void* __restrict__ Wh,
                            const void* __restrict__ bh,
                            const void* __restrict__ Wl,
                            const void* __restrict__ bl,
                            const uint32_t* __restrict__ xg,
                            const uint32_t* __restrict__ hg,
                            float* __restrict__ ws)
{
  const bool f32w = detect_f32_words((const uint32_t*)Wz, 64);
  uint16_t* wsh = (uint16_t*)ws;
  float*    wsf = ws;
  int i = blockIdx.x * 256 + threadIdx.x;
  if (i < 5376) {
    // bf16 weight tables, transposed+combined: Wt[col][k] = W[0][k][col]+W[1][k][col]
    float v = 0.0f;
    if (i < 3584) {                 // wzr: col 0-31 = z, 32-63 = r
      int col = i / STR, k = i - col * STR;
      if (k < 42) {
        const void* Wp = (col < 32) ? Wz : Wr;
        int j = (col < 32) ? col : col - 32;
        int src = k * 32 + j;
        v = wload(Wp, src, f32w) + wload(Wp, 1344 + src, f32w);
      }
    } else {                        // wh
      int t2 = i - 3584;
      int col = t2 / STR, k = t2 - col * STR;
      if (k < 42) {
        int src = k * 32 + col;
        v = wload(Wh, src, f32w) + wload(Wh, 1344 + src, f32w);
      }
    }
    wsh[i] = (uint16_t)bfrne(v);
  } else if (i < 5538) {
    int r = i - 5376;
    if      (r < 32)  wsf[2688 + r]       = wload(bz, r,     f32w);
    else if (r < 64)  wsf[2720 + (r-32)]  = wload(br, r-32,  f32w);
    else if (r < 96)  wsf[2752 + (r-64)]  = wload(bh, r-64,  f32w);
    else if (r < 160) wsf[2784 + (r-96)]  = wload(Wl, r-96,  f32w);
    else              wsf[2848 + (r-160)] = wload(bl, r-160, f32w);
  } else if (i == 5568) {
    wsf[2850] = detect_f32_words(xg, 256) ? 1.0f : 0.0f;
  } else if (i == 5569) {
    wsf[2851] = detect_f32_words(hg, 256) ? 1.0f : 0.0f;
  }
}

__global__ __launch_bounds__(128, 4) void dcrnn_kernel(
    const uint32_t* __restrict__ xg,    // x [N,10]: f32 or bf16-packed
    const uint32_t* __restrict__ hg,    // h [N,32]: f32 or bf16-packed
    const float*    __restrict__ ws,
    float* __restrict__ out0,           // f32 [N,2]
    float* __restrict__ outh)           // f32 [N,32]
{
  __shared__ __align__(16) uint16_t xh_u16[128 * STR];  // 14336 B A-tile

  const int t  = threadIdx.x;           // 0..127
  const int nd = blockIdx.x * 128 + t;
  const bool valid = nd < N_NODES;
  const float* wsf = ws;
  const uint16_t* wsh = (const uint16_t*)ws;
  const bool x_f32 = wsf[2850] != 0.0f;
  const bool h_f32 = wsf[2851] != 0.0f;

  // ---- stage this thread's node row: bf16 cols 0-9 x, 10-41 h, 42-47 pad ----
  uint32_t rw[24];
  #pragma unroll
  for (int i = 0; i < 24; i++) rw[i] = 0u;
  if (valid) {
    if (x_f32) {
      const float2* xr = (const float2*)((const float*)xg + (size_t)nd * 10);
      #pragma unroll
      for (int i = 0; i < 5; i++){ float2 v = xr[i]; rw[i] = pack2(v.x, v.y); }
    } else {
      const uint32_t* xr = xg + (size_t)nd * 5;
      #pragma unroll
      for (int i = 0; i < 5; i++) rw[i] = xr[i];     // already 2×bf16 per u32
    }
    if (h_f32) {
      const float4* hr = (const float4*)((const float*)hg + (size_t)nd * 32);
      #pragma unroll
      for (int i = 0; i < 8; i++){
        float4 v = hr[i];
        rw[5 + 2*i]     = pack2(v.x, v.y);
        rw[5 + 2*i + 1] = pack2(v.z, v.w);
      }
    } else {
      const uint4* hr = (const uint4*)(hg + (size_t)nd * 16);
      #pragma unroll
      for (int i = 0; i < 4; i++){
        uint4 v = hr[i];
        rw[5 + 4*i]     = v.x; rw[5 + 4*i + 1] = v.y;
        rw[5 + 4*i + 2] = v.z; rw[5 + 4*i + 3] = v.w;
      }
    }
  }
  {
    uint4* dst = (uint4*)(xh_u16 + t * STR);   // t*112 B, 16B-aligned
    #pragma unroll
    for (int c = 0; c < 6; c++)
      dst[c] = make_uint4(rw[4*c], rw[4*c+1], rw[4*c+2], rw[4*c+3]);
  }

  // ---- weight B-fragments straight from global ws (L2-resident, 10.75KB,
  //      shared by all blocks) — loaded ONCE per wave, loop-invariant ----
  const int l = t & 63, w = t >> 6;
  const int lo16 = l & 15, g = l >> 4;
  const short8 zero8 = {0,0,0,0,0,0,0,0};

  short8 bzr_lo[4], bzr_hi[4];          // GEMM1: nt=0,1 -> z; nt=2,3 -> r
  #pragma unroll
  for (int nt = 0; nt < 4; nt++){
    const uint16_t* brow = wsh + (nt*16 + lo16) * STR;
    bzr_lo[nt] = *(const short8*)(brow + g*8);
    bzr_hi[nt] = zero8;
    if (g < 2) bzr_hi[nt] = *(const short8*)(brow + 32 + g*8);
  }
  short8 bhf_lo[2], bhf_hi[2];          // GEMM2
  #pragma unroll
  for (int nt = 0; nt < 2; nt++){
    const uint16_t* brow = wsh + 3584 + (nt*16 + lo16) * STR;
    bhf_lo[nt] = *(const short8*)(brow + g*8);
    bhf_hi[nt] = zero8;
    if (g < 2) bhf_hi[nt] = *(const short8*)(brow + 32 + g*8);
  }

  const float bzc0 = wsf[2688 + lo16], bzc1 = wsf[2704 + lo16];
  const float brc0 = wsf[2720 + lo16], brc1 = wsf[2736 + lo16];
  const float bhc0 = wsf[2752 + lo16], bhc1 = wsf[2768 + lo16];

  __syncthreads();

  // ---- per-wave MFMA pipeline: wave w owns rows [64w, 64w+64) ----
  uint16_t* xwm = xh_u16 + (w * 64) * STR;

  #pragma unroll
  for (int mt = 0; mt < 4; mt++){
    const uint16_t* arow = xwm + (mt*16 + lo16) * STR;
    short8 a0 = *(const short8*)(arow + g*8);
    short8 a1 = zero8;
    if (g < 2) a1 = *(const short8*)(arow + 32 + g*8);

    // GEMM1: z (cols 0-31) and r (cols 32-63) preacts, bias in acc init
    f32x4 accZ0 = {bzc0,bzc0,bzc0,bzc0};
    f32x4 accZ1 = {bzc1,bzc1,bzc1,bzc1};
    f32x4 accR0 = {brc0,brc0,brc0,brc0};
    f32x4 accR1 = {brc1,brc1,brc1,brc1};
    accZ0 = __builtin_amdgcn_mfma_f32_16x16x32_bf16(a0, bzr_lo[0], accZ0, 0,0,0);
    accZ0 = __builtin_amdgcn_mfma_f32_16x16x32_bf16(a1, bzr_hi[0], accZ0, 0,0,0);
    accZ1 = __builtin_amdgcn_mfma_f32_16x16x32_bf16(a0, bzr_lo[1], accZ1, 0,0,0);
    accZ1 = __builtin_amdgcn_mfma_f32_16x16x32_bf16(a1, bzr_hi[1], accZ1, 0,0,0);
    accR0 = __builtin_amdgcn_mfma_f32_16x16x32_bf16(a0, bzr_lo[2], accR0, 0,0,0);
    accR0 = __builtin_amdgcn_mfma_f32_16x16x32_bf16(a1, bzr_hi[2], accR0, 0,0,0);
    accR1 = __builtin_amdgcn_mfma_f32_16x16x32_bf16(a0, bzr_lo[3], accR1, 0,0,0);
    accR1 = __builtin_amdgcn_mfma_f32_16x16x32_bf16(a1, bzr_hi[3], accR1, 0,0,0);

    // rh pass: save h (f32 from bf16), overwrite LDS cols 10-41 with r*h
    f32x4 hs0, hs1;
    #pragma unroll
    for (int q = 0; q < 4; q++){
      int row = mt*16 + g*4 + q;
      uint16_t* p0 = xwm + row*STR + 10 + lo16;
      uint16_t* p1 = xwm + row*STR + 26 + lo16;
      float h0 = bfdec(*p0), h1 = bfdec(*p1);
      float r0 = sigmoid_fast(accR0[q]);
      float r1 = sigmoid_fast(accR1[q]);
      *p0 = (uint16_t)bfrne(r0 * h0);
      *p1 = (uint16_t)bfrne(r1 * h1);
      hs0[q] = h0; hs1[q] = h1;
    }
    asm volatile("s_waitcnt lgkmcnt(0)" ::: "memory");  // cross-lane LDS RAW

    // GEMM2: h_tilde preacts from [x | r*h]
    f32x4 accH0 = {bhc0,bhc0,bhc0,bhc0};
    f32x4 accH1 = {bhc1,bhc1,bhc1,bhc1};
    short8 c0 = *(const short8*)(arow + g*8);
    short8 c1 = zero8;
    if (g < 2) c1 = *(const short8*)(arow + 32 + g*8);
    accH0 = __builtin_amdgcn_mfma_f32_16x16x32_bf16(c0, bhf_lo[0], accH0, 0,0,0);
    accH0 = __builtin_amdgcn_mfma_f32_16x16x32_bf16(c1, bhf_hi[0], accH0, 0,0,0);
    accH1 = __builtin_amdgcn_mfma_f32_16x16x32_bf16(c0, bhf_lo[1], accH1, 0,0,0);
    accH1 = __builtin_amdgcn_mfma_f32_16x16x32_bf16(c1, bhf_hi[1], accH1, 0,0,0);

    // blend + store h_new (f32, coalesced 64B per (g,q) sector);
    // stash relu(h_new) bf16 into dead cols 0-31 for the per-thread head
    #pragma unroll
    for (int q = 0; q < 4; q++){
      int row  = mt*16 + g*4 + q;
      int node = blockIdx.x*128 + w*64 + row;
      float z0 = sigmoid_fast(accZ0[q]);
      float z1 = sigmoid_fast(accZ1[q]);
      float t0 = tanh_fast(accH0[q]);
      float t1 = tanh_fast(accH1[q]);
      float hn0 = fmaf(z0, hs0[q] - t0, t0);
      float hn1 = fmaf(z1, hs1[q] - t1, t1);
      if (node < N_NODES){
        outh[(size_t)node*32 + lo16]      = hn0;
        outh[(size_t)node*32 + 16 + lo16] = hn1;
      }
      *(xwm + row*STR + lo16)      = (uint16_t)bfrne(fmaxf(hn0, 0.0f));
      *(xwm + row*STR + 16 + lo16) = (uint16_t)bfrne(fmaxf(hn1, 0.0f));
    }
  }

  // ---- head: per-thread matvec from own row's stash (4x aligned b128,
  //      stride 112B -> banks spread, throughput-bound not conflict-bound).
  //      Same-wave producer -> lgkmcnt drain suffices, no barrier. ----
  asm volatile("s_waitcnt lgkmcnt(0)" ::: "memory");
  if (valid){
    float o0 = wsf[2848], o1 = wsf[2849];
    const uint4* hq = (const uint4*)(xh_u16 + t * STR);   // cols 0..31
    #pragma unroll
    for (int i = 0; i < 4; i++){
      uint4 v = hq[i];
      uint32_t wv[4] = {v.x, v.y, v.z, v.w};
      #pragma unroll
      for (int j = 0; j < 4; j++){
        int c = i*8 + j*2;
        float v0 = bf_lo(wv[j]);
        float v1 = bf_hi(wv[j]);
        o0 = fmaf(v0, wsf[2784 + c],     o0);
        o1 = fmaf(v0, wsf[2816 + c],     o1);
        o0 = fmaf(v1, wsf[2784 + c + 1], o0);
        o1 = fmaf(v1, wsf[2816 + c + 1], o1);
      }
    }
    ((float2*)out0)[nd] = make_float2(o0, o1);   // coalesced 8B/thread
  }
}

extern "C" void kernel_launch(void* const* d_in, const int* in_sizes, int n_in,
                              void* d_out, int out_size, void* d_ws, size_t ws_size,
                              hipStream_t stream) {
  // setup_inputs order:
  // 0:x 1:edge_index(unused) 2:edge_weight(unused) 3:h
  // 4:W_z 5:b_z 6:W_r 7:b_r 8:W_h 9:b_h 10:W_lin 11:b_lin
  const uint32_t* x = (const uint32_t*)d_in[0];
  const uint32_t* h = (const uint32_t*)d_in[3];

  float* ws = (float*)d_ws;   // ~11.4 KB used

  prep_kernel<<<22, 256, 0, stream>>>(d_in[4], d_in[5], d_in[6], d_in[7],
                                      d_in[8], d_in[9], d_in[10], d_in[11],
                                      x, h, ws);

  float* outf = (float*)d_out;
  float* out0 = outf;                              // out   [N,2]  f32
  float* outh = outf + (size_t)2 * N_NODES;        // h_new [N,32] f32
  dcrnn_kernel<<<(N_NODES + 127) / 128, 128, 0, stream>>>(
      x, h, ws, out0, outh);
}

// Round 7
// 242.673 us; speedup vs baseline: 1.0246x; 1.0034x over previous
//
#include <hip/hip_runtime.h>
#include <stdint.h>

// Problem constants (reference: N=500000, F_IN=10, HID=32, OUT=2, d_in=42)
// Settled world model: x,h arrive bf16-packed (FETCH 41MB == bf16 sizes),
// weights f32 (runtime-detected either way); outputs f32: out [N,2] then
// h_new [N,32]. Harness threshold 0.088 (bf16 floor).
//
// Ladder: R8 MFMA rewrite 126.6->54.0us. R9 (head MFMA) regressed 61.5
// (scattered out0 stores -> RMW traffic). R10 (occupancy attack) 54us,
// occupancy counter unmoved at ~31% across 3 configs AND VGPR=64 ->
// allocator rematerialized the "hoisted" weight frags (R5 repeat).
// R11: shorten the per-wave chain itself.
//   * GEMM1 widened to N=96 (z|r|htilde_x, the x-part of GEMM2 folded in,
//     K<=10). GEMM2 becomes K=32 exact (pure r.h): 1 A-read + 2 MFMA,
//     C-in = GEMM1's htilde_x accs. One full read+wait phase removed.
//   * Column pairing: prep permutes W cols so lane c owns j=2c,2c+1.
//     RMW per q: 1 ds_read_b32 (h pair) + v_cvt_pk_bf16_f32 + 1
//     ds_write_b32 (was 2R+2W u16 + 2x 4-op bfrne). h_new stores become
//     float2 (halves store instrs). LDS ops/mt: 28 -> 15.
//   * Coalesced cooperative staging: h = 4 fully-coalesced uint4 loads
//     (was 4 loads x 64 sectors each = TA-path serialization), x = 5
//     coalesced u32 loads with magic-div scatter.
//   * launch_bounds(128,2) + asm pins on the 12 weight frags so they
//     STAY in registers (R5/R10: allocator rematerialized at 64 VGPR).
// Fragment layouts (gfx950 16x16x32 bf16): A row=l&15, k=(l>>4)*8+i;
// B col=l&15, k=(l>>4)*8+i; C/D col=l&15, row=(l>>4)*4+q (HW-verified).
static constexpr int N_NODES = 500000;
static constexpr int STR     = 56;     // LDS A-tile row stride in u16 (112 B)

typedef __attribute__((ext_vector_type(8))) short short8;   // 8 bf16, 4 VGPRs
typedef __attribute__((ext_vector_type(4))) float f32x4;

// d_ws layout:
//   u16 [0, 5376):    wzr_hx bf16 [96 cols][56 k]
//       cols 0-31 z, 32-63 r, 64-95 htilde_x (k<10 only, rest 0);
//       within each 32-block, col index c<16 -> j=2c, c>=16 -> j=2(c-16)+1
//   u16 [5376, 6400): whh bf16 [32 cols][32 k]  (k = Wh rows 10..41,
//       cols paired like above)
//   f32 [3200): bz'[32] paired  [3232): br'[32]  [3264): bh'[32]
//   f32 [3296): Wl[2][32] natural  [3360): bl[2]
//   f32 [3362): x_f32 flag  [3363): h_f32 flag

__device__ __forceinline__ float bfdec(uint32_t b){
  union{uint32_t u; float f;} c; c.u = b << 16; return c.f;
}
__device__ __forceinline__ float bf_lo(uint32_t u){ union{uint32_t u; float f;} c; c.u = u << 16; return c.f; }
__device__ __forceinline__ float bf_hi(uint32_t u){ union{uint32_t u; float f;} c; c.u = u & 0xffff0000u; return c.f; }
__device__ __forceinline__ uint32_t bfrne(float f){   // f32 -> bf16 (RNE)
  union{float f; uint32_t u;} c; c.f = f;
  return (c.u + 0x7fffu + ((c.u >> 16) & 1u)) >> 16;
}
__device__ __forceinline__ uint32_t pack2(float a, float b){
  return bfrne(a) | (bfrne(b) << 16);
}
__device__ __forceinline__ uint32_t cvtpk_bf16(float lo, float hi){
  uint32_t r;
  asm("v_cvt_pk_bf16_f32 %0, %1, %2" : "=v"(r) : "v"(lo), "v"(hi));
  return r;
}
__device__ __forceinline__ float sigmoid_fast(float x){
  float e = __expf(-x);
  return __builtin_amdgcn_rcpf(1.0f + e);
}
__device__ __forceinline__ float tanh_fast(float x){
  float e = __expf(2.0f * x);
  return 1.0f - 2.0f * __builtin_amdgcn_rcpf(e + 1.0f);
}

// bf16-packed data: lo u16 decodes to |v| <~ 6; f32 data: lo u16 is random
// mantissa bits -> decoded exponent uniform -> max explodes past 1e6 w.p.~1.
__device__ bool detect_f32_words(const uint32_t* w, int K){
  float m = 0.0f;
  for (int i = 0; i < K; i++) m = fmaxf(m, fabsf(bfdec(w[i] & 0xffffu)));
  return !(m < 1e6f);   // NaN-safe: NaN => f32
}
__device__ __forceinline__ float wload(const void* p, int idx, bool f32w){
  if (f32w) return ((const float*)p)[idx];
  return bfdec(((const uint16_t*)p)[idx]);
}

__global__ void prep_kernel(const void* __restrict__ Wz,
                            const void* __restrict__ bz,
                            const void* __restrict__ Wr,
                            const void* __restrict__ br,
                            const void* __restrict__ Wh,
                            const void* __restrict__ bh,
                            const void* __restrict__ Wl,
                            const void* __restrict__ bl,
                            const uint32_t* __restrict__ xg,
                            const uint32_t* __restrict__ hg,
                            float* __restrict__ ws)
{
  const bool f32w = detect_f32_words((const uint32_t*)Wz, 64);
  uint16_t* wsh = (uint16_t*)ws;
  float*    wsf = ws;
  int i = blockIdx.x * 256 + threadIdx.x;
  if (i < 5376) {
    // wzr_hx: col cc, k. paired j within each 32-col block.
    int cc = i / STR, k = i - cc * STR;
    int blk = cc >> 5, within = cc & 31;
    int j = 2 * (within & 15) + (within >> 4);
    float v = 0.0f;
    if (blk == 0) {
      if (k < 42) { int s = k*32 + j; v = wload(Wz, s, f32w) + wload(Wz, 1344 + s, f32w); }
    } else if (blk == 1) {
      if (k < 42) { int s = k*32 + j; v = wload(Wr, s, f32w) + wload(Wr, 1344 + s, f32w); }
    } else {
      if (k < 10) { int s = k*32 + j; v = wload(Wh, s, f32w) + wload(Wh, 1344 + s, f32w); }
    }
    wsh[i] = (uint16_t)bfrne(v);
  } else if (i < 6400) {
    // whh [32 cols][32 k]: k -> Wh row 10+k; cols paired.
    int t2 = i - 5376;
    int cc = t2 >> 5, k = t2 & 31;
    int j = 2 * (cc & 15) + (cc >> 4);
    int s = (10 + k)*32 + j;
    wsh[i] = (uint16_t)bfrne(wload(Wh, s, f32w) + wload(Wh, 1344 + s, f32w));
  } else if (i < 6496) {
    // paired biases: dst[blk*32 + within] = b[j]
    int r = i - 6400;
    int blk = r >> 5, within = r & 31;
    int j = 2 * (within & 15) + (within >> 4);
    const void* bp = (blk == 0) ? bz : (blk == 1) ? br : bh;
    wsf[3200 + r] = wload(bp, j, f32w);
  } else if (i < 6562) {
    int r = i - 6496;
    if (r < 64) wsf[3296 + r] = wload(Wl, r, f32w);
    else        wsf[3360 + (r-64)] = wload(bl, r-64, f32w);
  } else if (i == 6592) {
    wsf[3362] = detect_f32_words(xg, 256) ? 1.0f : 0.0f;
  } else if (i == 6593) {
    wsf[3363] = detect_f32_words(hg, 256) ? 1.0f : 0.0f;
  }
}

__global__ __launch_bounds__(128, 2) void dcrnn_kernel(
    const uint32_t* __restrict__ xg,    // x [N,10]: f32 or bf16-packed
    const uint32_t* __restrict__ hg,    // h [N,32]: f32 or bf16-packed
    const float*    __restrict__ ws,
    float* __restrict__ out0,           // f32 [N,2]
    float* __restrict__ outh)           // f32 [N,32]
{
  __shared__ __align__(16) uint16_t xh_u16[128 * STR];  // 14336 B A-tile

  const int t  = threadIdx.x;           // 0..127
  const int nd = blockIdx.x * 128 + t;
  const bool valid = nd < N_NODES;
  const float* wsf = ws;
  const uint16_t* wsh = (const uint16_t*)ws;
  const bool x_f32 = wsf[3362] != 0.0f;
  const bool h_f32 = wsf[3363] != 0.0f;

  // ---- staging: natural layout cols 0-9 x, 10-41 h, 42-47 zero ----
  if (x_f32 || h_f32) {
    // slow fallback: per-thread row (correctness path; bf16 is the fast case)
    uint32_t rw[24];
    #pragma unroll
    for (int i = 0; i < 24; i++) rw[i] = 0u;
    if (valid) {
      if (x_f32) {
        const float2* xr = (const float2*)((const float*)xg + (size_t)nd * 10);
        #pragma unroll
        for (int i = 0; i < 5; i++){ float2 v = xr[i]; rw[i] = pack2(v.x, v.y); }
      } else {
        const uint32_t* xr = xg + (size_t)nd * 5;
        #pragma unroll
        for (int i = 0; i < 5; i++) rw[i] = xr[i];
      }
      if (h_f32) {
        const float4* hr = (const float4*)((const float*)hg + (size_t)nd * 32);
        #pragma unroll
        for (int i = 0; i < 8; i++){
          float4 v = hr[i];
          rw[5 + 2*i]     = pack2(v.x, v.y);
          rw[5 + 2*i + 1] = pack2(v.z, v.w);
        }
      } else {
        const uint4* hr = (const uint4*)(hg + (size_t)nd * 16);
        #pragma unroll
        for (int i = 0; i < 4; i++){
          uint4 v = hr[i];
          rw[5 + 4*i] = v.x; rw[5 + 4*i + 1] = v.y;
          rw[5 + 4*i + 2] = v.z; rw[5 + 4*i + 3] = v.w;
        }
      }
    }
    uint4* dst = (uint4*)(xh_u16 + t * STR);
    #pragma unroll
    for (int c = 0; c < 6; c++)
      dst[c] = make_uint4(rw[4*c], rw[4*c+1], rw[4*c+2], rw[4*c+3]);
  } else {
    // fast path: fully-coalesced cooperative loads + LDS scatter.
    // x: 128 nodes x 5 u32 = 640 u32, 5 coalesced loads
    const uint32_t* xbase = xg + (size_t)blockIdx.x * 640;
    #pragma unroll
    for (int i = 0; i < 5; i++){
      int idx = i * 128 + t;
      uint32_t v = 0u;
      if ((size_t)blockIdx.x * 640 + idx < (size_t)N_NODES * 5) v = xbase[idx];
      int node = (idx * 6554) >> 15;          // idx/5, exact for idx<640
      int col  = idx - node * 5;
      *(uint32_t*)(xh_u16 + node * STR + col * 2) = v;
    }
    // h: 128 nodes x 4 uint4 = 512 uint4, 4 coalesced loads
    const uint4* hbase = (const uint4*)(hg + (size_t)blockIdx.x * 2048);
    #pragma unroll
    for (int i = 0; i < 4; i++){
      int idx = i * 128 + t;
      uint4 v = make_uint4(0u,0u,0u,0u);
      if ((size_t)blockIdx.x * 512 + idx < (size_t)N_NODES * 4) v = hbase[idx];
      int node = idx >> 2, chunk = idx & 3;
      *(uint4*)(xh_u16 + node * STR + 10 + chunk * 8) = v;
    }
    // zero pad cols 42..47 of own row (NaN-safety for a1 x zero-W MFMAs)
    *(uint32_t*)(xh_u16 + t * STR + 42) = 0u;
    *(uint32_t*)(xh_u16 + t * STR + 44) = 0u;
    *(uint32_t*)(xh_u16 + t * STR + 46) = 0u;
  }

  // ---- weight fragments from global ws (L2-resident), pinned in VGPRs ----
  const int l = t & 63, w = t >> 6;
  const int lo16 = l & 15, g = l >> 4;
  const short8 zero8 = {0,0,0,0,0,0,0,0};

  short8 b_lo[6], b_hi[4];
  #pragma unroll
  for (int nt = 0; nt < 6; nt++){
    const uint16_t* brow = wsh + (nt*16 + lo16) * STR;
    b_lo[nt] = *(const short8*)(brow + g*8);
  }
  #pragma unroll
  for (int nt = 0; nt < 4; nt++){
    const uint16_t* brow = wsh + (nt*16 + lo16) * STR;
    b_hi[nt] = (g < 2) ? *(const short8*)(brow + 32 + g*8) : zero8;
  }
  short8 bhh[2];
  #pragma unroll
  for (int nt = 0; nt < 2; nt++){
    const uint16_t* brow = wsh + 5376 + (nt*16 + lo16) * 32;
    bhh[nt] = *(const short8*)(brow + g*8);
  }
  // pin: forbid rematerialization-from-global inside the loop (R5/R10 bug)
  #pragma unroll
  for (int nt = 0; nt < 6; nt++) asm("" : "+v"(b_lo[nt]));
  #pragma unroll
  for (int nt = 0; nt < 4; nt++) asm("" : "+v"(b_hi[nt]));
  asm("" : "+v"(bhh[0]), "+v"(bhh[1]));

  const float bzc0 = wsf[3200 + lo16], bzc1 = wsf[3216 + lo16];
  const float brc0 = wsf[3232 + lo16], brc1 = wsf[3248 + lo16];
  const float bhc0 = wsf[3264 + lo16], bhc1 = wsf[3280 + lo16];

  __syncthreads();

  // ---- per-wave MFMA pipeline: wave w owns tile rows [64w, 64w+64) ----
  uint16_t* xwm = xh_u16 + (w * 64) * STR;

  #pragma unroll
  for (int mt = 0; mt < 4; mt++){
    uint16_t* arow = xwm + (mt*16 + lo16) * STR;
    short8 a0 = *(const short8*)(arow);          // k 0..31 (x + h lo)
    short8 a1 = zero8;
    if (g < 2) a1 = *(const short8*)(arow + 32); // k 32..47 (+pad)
    // NB: fragment k-index = (l>>4)*8+i -> a0 at arow + g*8, a1 at +32+g*8
    a0 = *(const short8*)(arow + g*8);
    if (g < 2) a1 = *(const short8*)(arow + 32 + g*8);

    // GEMM1 (N=96): z, r, htilde_x. Bias rides in acc init.
    f32x4 accZ0 = {bzc0,bzc0,bzc0,bzc0};
    f32x4 accZ1 = {bzc1,bzc1,bzc1,bzc1};
    f32x4 accR0 = {brc0,brc0,brc0,brc0};
    f32x4 accR1 = {brc1,brc1,brc1,brc1};
    f32x4 accH0 = {bhc0,bhc0,bhc0,bhc0};
    f32x4 accH1 = {bhc1,bhc1,bhc1,bhc1};
    accZ0 = __builtin_amdgcn_mfma_f32_16x16x32_bf16(a0, b_lo[0], accZ0, 0,0,0);
    accZ0 = __builtin_amdgcn_mfma_f32_16x16x32_bf16(a1, b_hi[0], accZ0, 0,0,0);
    accZ1 = __builtin_amdgcn_mfma_f32_16x16x32_bf16(a0, b_lo[1], accZ1, 0,0,0);
    accZ1 = __builtin_amdgcn_mfma_f32_16x16x32_bf16(a1, b_hi[1], accZ1, 0,0,0);
    accR0 = __builtin_amdgcn_mfma_f32_16x16x32_bf16(a0, b_lo[2], accR0, 0,0,0);
    accR0 = __builtin_amdgcn_mfma_f32_16x16x32_bf16(a1, b_hi[2], accR0, 0,0,0);
    accR1 = __builtin_amdgcn_mfma_f32_16x16x32_bf16(a0, b_lo[3], accR1, 0,0,0);
    accR1 = __builtin_amdgcn_mfma_f32_16x16x32_bf16(a1, b_hi[3], accR1, 0,0,0);
    accH0 = __builtin_amdgcn_mfma_f32_16x16x32_bf16(a0, b_lo[4], accH0, 0,0,0);
    accH1 = __builtin_amdgcn_mfma_f32_16x16x32_bf16(a0, b_lo[5], accH1, 0,0,0);

    // RMW: lane c handles j=2c,2c+1 of rows g*4+q -> h pair is ONE b32.
    // Write r.h pair (packed bf16) into cols 0..31 (k-aligned for GEMM2).
    // Same-row read-before-write is safe: wave LDS ops execute in order.
    f32x4 hs0, hs1;
    #pragma unroll
    for (int q = 0; q < 4; q++){
      int row = mt*16 + g*4 + q;
      uint32_t hp = *(const uint32_t*)(xwm + row*STR + 10 + 2*lo16);
      float h0 = bf_lo(hp), h1 = bf_hi(hp);
      float r0 = sigmoid_fast(accR0[q]);
      float r1 = sigmoid_fast(accR1[q]);
      *(uint32_t*)(xwm + row*STR + 2*lo16) = cvtpk_bf16(r0*h0, r1*h1);
      hs0[q] = h0; hs1[q] = h1;
    }
    asm volatile("s_waitcnt lgkmcnt(0)" ::: "memory");  // cross-lane LDS RAW

    // GEMM2: K=32 exact, A = r.h region (cols 0..31), C-in = accH.
    short8 aR = *(const short8*)(arow + g*8);   // rh pairs, k 0..31
    accH0 = __builtin_amdgcn_mfma_f32_16x16x32_bf16(aR, bhh[0], accH0, 0,0,0);
    accH1 = __builtin_amdgcn_mfma_f32_16x16x32_bf16(aR, bhh[1], accH1, 0,0,0);

    // blend + float2 h_new store + packed relu stash for the head
    #pragma unroll
    for (int q = 0; q < 4; q++){
      int row  = mt*16 + g*4 + q;
      int node = blockIdx.x*128 + w*64 + row;
      float z0 = sigmoid_fast(accZ0[q]);
      float z1 = sigmoid_fast(accZ1[q]);
      float t0 = tanh_fast(accH0[q]);
      float t1 = tanh_fast(accH1[q]);
      float hn0 = fmaf(z0, hs0[q] - t0, t0);    // j = 2*lo16
      float hn1 = fmaf(z1, hs1[q] - t1, t1);    // j = 2*lo16+1
      if (node < N_NODES)
        *(float2*)(outh + (size_t)node*32 + 2*lo16) = make_float2(hn0, hn1);
      *(uint32_t*)(xwm + row*STR + 2*lo16) =
          cvtpk_bf16(fmaxf(hn0, 0.0f), fmaxf(hn1, 0.0f));
    }
  }

  // ---- head: per-thread matvec from own row's packed stash ----
  asm volatile("s_waitcnt lgkmcnt(0)" ::: "memory");
  if (valid){
    float o0 = wsf[3360], o1 = wsf[3361];
    const uint4* hq = (const uint4*)(xh_u16 + t * STR);   // u32 pairs, j natural
    #pragma unroll
    for (int i = 0; i < 4; i++){
      uint4 v = hq[i];
      uint32_t wv[4] = {v.x, v.y, v.z, v.w};
      #pragma unroll
      for (int p = 0; p < 4; p++){
        int j = i*8 + p*2;
        float v0 = bf_lo(wv[p]);               // h_new[j]
        float v1 = bf_hi(wv[p]);               // h_new[j+1]
        o0 = fmaf(v0, wsf[3296 + j],     o0);
        o1 = fmaf(v0, wsf[3328 + j],     o1);
        o0 = fmaf(v1, wsf[3296 + j + 1], o0);
        o1 = fmaf(v1, wsf[3328 + j + 1], o1);
      }
    }
    ((float2*)out0)[nd] = make_float2(o0, o1);   // coalesced 8B/thread
  }
}

extern "C" void kernel_launch(void* const* d_in, const int* in_sizes, int n_in,
                              void* d_out, int out_size, void* d_ws, size_t ws_size,
                              hipStream_t stream) {
  // setup_inputs order:
  // 0:x 1:edge_index(unused) 2:edge_weight(unused) 3:h
  // 4:W_z 5:b_z 6:W_r 7:b_r 8:W_h 9:b_h 10:W_lin 11:b_lin
  const uint32_t* x = (const uint32_t*)d_in[0];
  const uint32_t* h = (const uint32_t*)d_in[3];

  float* ws = (float*)d_ws;   // ~13.5 KB used

  prep_kernel<<<26, 256, 0, stream>>>(d_in[4], d_in[5], d_in[6], d_in[7],
                                      d_in[8], d_in[9], d_in[10], d_in[11],
                                      x, h, ws);

  float* outf = (float*)d_out;
  float* out0 = outf;                              // out   [N,2]  f32
  float* outh = outf + (size_t)2 * N_NODES;        // h_new [N,32] f32
  dcrnn_kernel<<<(N_NODES + 127) / 128, 128, 0, stream>>>(
      x, h, ws, out0, outh);
}